// Round 4
// baseline (113.984 us; speedup 1.0000x reference)
//
#include <hip/hip_runtime.h>
#include <math.h>

#define NROWS 65536   // B*T = 1024*64

typedef short bf16x8 __attribute__((ext_vector_type(8)));
typedef float f32x4  __attribute__((ext_vector_type(4)));
typedef float f32x2  __attribute__((ext_vector_type(2)));
typedef unsigned int u32x2 __attribute__((ext_vector_type(2)));

__device__ __forceinline__ unsigned short f2bf(float x){
    unsigned int u = __float_as_uint(x);
    u += 0x7FFFu + ((u >> 16) & 1u);      // RNE
    return (unsigned short)(u >> 16);
}
__device__ __forceinline__ unsigned int pkbf(float lo, float hi){
    unsigned int r;
    asm("v_cvt_pk_bf16_f32 %0, %1, %2" : "=v"(r) : "v"(lo), "v"(hi));
    return r;
}
__device__ __forceinline__ f32x2 sp2(float x){ return (f32x2){x, x}; }

template<int CTRL, int RM>
__device__ __forceinline__ float dpp_add(float v){
    int m = __builtin_amdgcn_update_dpp(0, __float_as_int(v), CTRL, RM, 0xF, 1);
    return v + __int_as_float(m);
}
// butterfly over 8 lanes: all 8 lanes get the total
__device__ __forceinline__ float bfly8_add(float v){
    v = dpp_add<0xB1, 0xF>(v);     // quad_perm [1,0,3,2]
    v = dpp_add<0x4E, 0xF>(v);     // quad_perm [2,3,0,1]
    v = dpp_add<0x141, 0xF>(v);    // row_half_mirror
    return v;
}
// sum over the 4 lanes {lm, lm+16, lm+32, lm+48} (reduce over lq)
__device__ __forceinline__ float red4_lq(float v){
    v += __int_as_float(__builtin_amdgcn_ds_swizzle(__float_as_int(v), 0x401F)); // lane^16
    v += __shfl_xor(v, 32, 64);                                                  // lane^32
    return v;
}
__device__ __forceinline__ float fast_tanh(float x){
    float e = __builtin_amdgcn_exp2f(x * 2.8853900817779268f);
    return 1.f - 2.f * __builtin_amdgcn_rcpf(e + 1.f);
}

// ---- prep: weights -> MFMA fragment order; folded qk matrix C ----
__global__ __launch_bounds__(256) void prep_kernel(
    const float* __restrict__ W2, const float* __restrict__ W1,
    const float* __restrict__ Wq, const float* __restrict__ Wk,
    unsigned short* __restrict__ w2frag, unsigned short* __restrict__ w1frag,
    float* __restrict__ Cqk)
{
    const int bx = blockIdx.x, t = threadIdx.x;
    if (bx < 128){
        const int ct = bx >> 3, kk = bx & 7;
        #pragma unroll
        for (int s = 0; s < 2; ++s){
            int f = t * 2 + s;
            int lane = f >> 3, e = f & 7;
            int k = kk * 32 + (lane >> 4) * 8 + e;
            int c = ct * 16 + (lane & 15);
            w2frag[(size_t)(ct * 8 + kk) * 512 + f] = f2bf(W2[k * 256 + c]);
        }
    } else if (bx == 128){
        #pragma unroll
        for (int s = 0; s < 32; ++s){
            int flat = t * 32 + s;
            int ct = flat >> 9, r = flat & 511;
            int lane = r >> 3, e = r & 7;
            int k = (lane >> 4) * 8 + e;
            int c = ct * 16 + (lane & 15);
            w1frag[flat] = (k < 23) ? f2bf(W1[k * 256 + c]) : (unsigned short)0;
        }
    } else {
        // Cqk[(h*5+f)*8+d] = scale * sum_kk Wk[f*15+h*5+kk] * Wq[d*15+h*5+kk]
        if (t < 120){
            int h = t / 40, rem = t % 40, f = rem >> 3, d = rem & 7;
            float acc = 0.f;
            #pragma unroll
            for (int kk = 0; kk < 5; ++kk)
                acc += Wk[f * 15 + h * 5 + kk] * Wq[d * 15 + h * 5 + kk];
            Cqk[t] = acc * 0.64519834f;   // (1/sqrt5)*log2(e)
        }
    }
}

// ---- fused actor: 256 threads per block, block = 32 i-rows of one batch.
//      2 blocks per batch -> 4 independent blocks resident per CU (vs 2 at 512thr),
//      same per-lane work, finer barrier granularity. ----
__global__ __launch_bounds__(256, 4) void actor_kernel(
    const float* __restrict__ state, const float* __restrict__ noise,
    const float* __restrict__ Cqk,
    const float* __restrict__ Wv,
    const unsigned short* __restrict__ w1frag, const float* __restrict__ b1,
    const unsigned short* __restrict__ w2frag, const float* __restrict__ b2,
    const float* __restrict__ Wmu, const float* __restrict__ bmu,
    const float* __restrict__ Wls, const float* __restrict__ bls,
    float* __restrict__ action_out, float* __restrict__ logprob_out)
{
    // union A: {sLDS 576f, pjLDS 384f, qkLDS 32*20f} (6400 B) then h1LDS 32x264 bf16 (16896 B)
    __shared__ __align__(16) unsigned char uniA[32 * 264 * 2];
    float* sLDS  = (float*)uniA;              // 64*9 (all 64 j-rows)
    float* pjLDS = sLDS + 576;                // 32*12: pairs (c(j), c(j+32)) for c=s0..3,sn,cs
    float* qkLDS = pjLDS + 384;               // 32*20: own i-rows, prescaled qk
    unsigned short* h1LDS = (unsigned short*)uniA;   // 32 x 264 (stride 264)
    __shared__ __align__(16) unsigned short x0LDS[32 * 40];
    __shared__ __align__(16) float headLDS[4 * 32 * 4];

    const int t    = threadIdx.x;
    const int lane = t & 63;
    const int w    = t >> 6;                  // 0..3
    const int lm   = lane & 15;
    const int lq   = lane >> 4;
    const int b    = blockIdx.x >> 1;
    const int R0   = (blockIdx.x & 1) * 32;   // first owned i-row

    // ---- phase 0 (merged): full state load + qk fold (own rows) + sincos ----
    {
        const float* sb = &state[(size_t)b * 512];
        float v0 = sb[t];
        float v1 = sb[256 + t];
        int r = t >> 3, c = t & 7;            // r in 0..31
        sLDS[r * 9 + c] = v0;
        sLDS[(r + 32) * 9 + c] = v1;
        if (c < 4){
            pjLDS[r * 12 + c * 2 + 0] = v0;
            pjLDS[r * 12 + c * 2 + 1] = v1;
        }
        if (t < 96){
            const int rl = t & 31, h = t >> 5;
            const int row = R0 + rl;
            f32x4 sA = *(const f32x4*)&sb[row * 8];
            f32x4 sB = *(const f32x4*)&sb[row * 8 + 4];
            #pragma unroll
            for (int f = 0; f < 5; ++f){
                const float* cp = &Cqk[(h * 5 + f) * 8];
                f32x4 cA = *(const f32x4*)cp;
                f32x4 cB = *(const f32x4*)(cp + 4);
                float acc = sA[0]*cA[0] + sA[1]*cA[1] + sA[2]*cA[2] + sA[3]*cA[3]
                          + sB[0]*cB[0] + sB[1]*cB[1] + sB[2]*cB[2] + sB[3]*cB[3];
                qkLDS[rl * 20 + h * 5 + f] = acc;
            }
        } else if (t >= 192){
            const int j = t - 192;            // 0..63
            float ang = 1.5707963267948966f - sb[j * 8 + 7];
            float sn, cs;
            __sincosf(ang, &sn, &cs);
            int base = (j & 31) * 12 + (j >> 5);
            pjLDS[base + 8]  = sn;
            pjLDS[base + 10] = cs;
        }
    }
    __syncthreads();

    // ---- phase 1: attention, 2 j's per iter via packed fp32; self-term
    //      corrected analytically AFTER the loop (no per-iter masking) ----
    {
        const int il = lane >> 3;
        const int js = lane & 7;
        const int iL = w * 8 + il;            // local 0..31
        const int i  = R0 + iL;               // global row in batch
        const float si0 = sLDS[i * 9 + 0], si1 = sLDS[i * 9 + 1];
        const float si2 = sLDS[i * 9 + 2], si3 = sLDS[i * 9 + 3];
        float qkv[16];
        *(f32x4*)&qkv[0]  = *(const f32x4*)&qkLDS[iL * 20 + 0];
        *(f32x4*)&qkv[4]  = *(const f32x4*)&qkLDS[iL * 20 + 4];
        *(f32x4*)&qkv[8]  = *(const f32x4*)&qkLDS[iL * 20 + 8];
        *(f32x4*)&qkv[12] = *(const f32x4*)&qkLDS[iL * 20 + 12];

        f32x2 s0 = {0.f,0.f}, s1 = {0.f,0.f}, s2 = {0.f,0.f};
        f32x2 g0[5], g1[5], g2[5];
        #pragma unroll
        for (int f = 0; f < 5; ++f){ g0[f] = sp2(0.f); g1[f] = sp2(0.f); g2[f] = sp2(0.f); }

        #pragma unroll
        for (int jj = 0; jj < 4; ++jj){
            const int jb = jj * 8 + js;                  // handles j = jb and jb+32
            const f32x2* pp = (const f32x2*)&pjLDS[jb * 12];
            f32x2 p0 = pp[0], p1 = pp[1], p2 = pp[2], p3 = pp[3];
            f32x2 sn = pp[4], cs = pp[5];
            f32x2 d0 = p0 - sp2(si0), d1 = p1 - sp2(si1);
            f32x2 d2 = p2 - sp2(si2), d3 = p3 - sp2(si3);
            // r^2 is rotation-invariant; +1e-30 keeps self lane finite
            f32x2 r2v = d0 * d0 + d1 * d1 + sp2(1e-30f);
            f32x2 xn0 = d0 * cs - d1 * sn, yn0 = d0 * sn + d1 * cs;
            f32x2 xn1 = d2 * cs - d3 * sn, yn1 = d2 * sn + d3 * cs;
            f32x2 inv_r;
            inv_r.x = __builtin_amdgcn_rsqf(r2v.x);
            inv_r.y = __builtin_amdgcn_rsqf(r2v.y);
            f32x2 rv  = r2v * inv_r;
            f32x2 arg = rv * sp2(7.2134752f) - sp2(2.8853901f);   // log2(e)*(5r-2)
            f32x2 f4;
            f4.x = __builtin_amdgcn_rcpf(1.f + __builtin_amdgcn_exp2f(arg.x));
            f4.y = __builtin_amdgcn_rcpf(1.f + __builtin_amdgcn_exp2f(arg.y));
            f32x2 f0 = xn0 * inv_r, f1 = yn0 * inv_r;
            f32x2 sc0 = f0*sp2(qkv[0])  + f1*sp2(qkv[1])  + xn1*sp2(qkv[2])  + yn1*sp2(qkv[3])  + f4*sp2(qkv[4]);
            f32x2 sc1 = f0*sp2(qkv[5])  + f1*sp2(qkv[6])  + xn1*sp2(qkv[7])  + yn1*sp2(qkv[8])  + f4*sp2(qkv[9]);
            f32x2 sc2 = f0*sp2(qkv[10]) + f1*sp2(qkv[11]) + xn1*sp2(qkv[12]) + yn1*sp2(qkv[13]) + f4*sp2(qkv[14]);
            f32x2 e0, e1, e2;
            e0.x = __builtin_amdgcn_exp2f(sc0.x);  e0.y = __builtin_amdgcn_exp2f(sc0.y);
            e1.x = __builtin_amdgcn_exp2f(sc1.x);  e1.y = __builtin_amdgcn_exp2f(sc1.y);
            e2.x = __builtin_amdgcn_exp2f(sc2.x);  e2.y = __builtin_amdgcn_exp2f(sc2.y);
            s0 += e0; s1 += e1; s2 += e2;
            g0[0] += e0*f0; g0[1] += e0*f1; g0[2] += e0*xn1; g0[3] += e0*yn1; g0[4] += e0*f4;
            g1[0] += e1*f0; g1[1] += e1*f1; g1[2] += e1*xn1; g1[3] += e1*yn1; g1[4] += e1*f4;
            g2[0] += e2*f0; g2[1] += e2*f1; g2[2] += e2*xn1; g2[3] += e2*yn1; g2[4] += e2*f4;
        }
        // collapse pair lanes, then 8-lane butterfly
        float S0 = s0.x + s0.y, S1 = s1.x + s1.y, S2 = s2.x + s2.y;
        float G0[5], G1[5], G2[5];
        #pragma unroll
        for (int f = 0; f < 5; ++f){
            G0[f] = bfly8_add(g0[f].x + g0[f].y);
            G1[f] = bfly8_add(g1[f].x + g1[f].y);
            G2[f] = bfly8_add(g2[f].x + g2[f].y);
        }
        S0 = bfly8_add(S0); S1 = bfly8_add(S1); S2 = bfly8_add(S2);

        // analytic self-term removal: features at j==i are (0,0,0,0,f4s)
        {
            float argS = 7.2134752e-15f - 2.8853901f;
            float f4s  = __builtin_amdgcn_rcpf(1.f + __builtin_amdgcn_exp2f(argS));
            float es0 = __builtin_amdgcn_exp2f(f4s * qkv[4]);
            float es1 = __builtin_amdgcn_exp2f(f4s * qkv[9]);
            float es2 = __builtin_amdgcn_exp2f(f4s * qkv[14]);
            S0 -= es0; S1 -= es1; S2 -= es2;
            G0[4] -= es0 * f4s; G1[4] -= es1 * f4s; G2[4] -= es2 * f4s;
        }
        float i0 = __builtin_amdgcn_rcpf(S0);
        float i1 = __builtin_amdgcn_rcpf(S1);
        float i2 = __builtin_amdgcn_rcpf(S2);

        // x0: att cols (lane js writes m = 2js, 2js+1), state cols, zero pad
        #pragma unroll
        for (int mm = 0; mm < 2; ++mm){
            int m = js * 2 + mm;
            if (m < 15){
                float A0 = (m < 5) ? G0[0] : (m < 10) ? G1[0] : G2[0];
                float A1 = (m < 5) ? G0[1] : (m < 10) ? G1[1] : G2[1];
                float A2 = (m < 5) ? G0[2] : (m < 10) ? G1[2] : G2[2];
                float A3 = (m < 5) ? G0[3] : (m < 10) ? G1[3] : G2[3];
                float A4 = (m < 5) ? G0[4] : (m < 10) ? G1[4] : G2[4];
                float I  = (m < 5) ? i0    : (m < 10) ? i1    : i2;
                float av = (A0 * Wv[m] + A1 * Wv[15 + m] + A2 * Wv[30 + m]
                          + A3 * Wv[45 + m] + A4 * Wv[60 + m]) * I;
                x0LDS[iL * 40 + m] = f2bf(av);
            }
        }
        x0LDS[iL * 40 + 15 + js] = f2bf(sLDS[i * 9 + js]);
        x0LDS[iL * 40 + 23 + js] = 0;
        if (js == 0) x0LDS[iL * 40 + 31] = 0;
    }
    __syncthreads();

    // ---- phase 2: h1^T = mfma(W1^T-frag, x0-frag); wave w -> coltiles w*4..w*4+3 ----
    {
        bf16x8 afr[2];
        #pragma unroll
        for (int rt = 0; rt < 2; ++rt)
            afr[rt] = *(const bf16x8*)&x0LDS[(rt * 16 + lm) * 40 + lq * 8];
        #pragma unroll
        for (int ci = 0; ci < 4; ++ci){
            const int ct = w * 4 + ci;
            bf16x8 bfr = *(const bf16x8*)&w1frag[(size_t)ct * 512 + lane * 8];
            f32x4 bb = *(const f32x4*)&b1[ct * 16 + lq * 4];
            #pragma unroll
            for (int rt = 0; rt < 2; ++rt){
                f32x4 c0 = {0.f, 0.f, 0.f, 0.f};
                c0 = __builtin_amdgcn_mfma_f32_16x16x32_bf16(bfr, afr[rt], c0, 0, 0, 0);
                float h0 = fmaxf(c0[0] + bb[0], 0.f);
                float h1v = fmaxf(c0[1] + bb[1], 0.f);
                float h2v = fmaxf(c0[2] + bb[2], 0.f);
                float h3v = fmaxf(c0[3] + bb[3], 0.f);
                u32x2 pk; pk.x = pkbf(h0, h1v); pk.y = pkbf(h2v, h3v);
                *(u32x2*)&h1LDS[(rt * 16 + lm) * 264 + ct * 16 + lq * 4] = pk;
            }
        }
    }
    __syncthreads();

    // ---- phase 3: h2^T = mfma(W2^T-frag, h1-frag); head dots + 4-lane reduce ----
    {
        f32x4 acc[2][4];
        #pragma unroll
        for (int rt = 0; rt < 2; ++rt)
            #pragma unroll
            for (int ci = 0; ci < 4; ++ci) acc[rt][ci] = (f32x4){0.f, 0.f, 0.f, 0.f};

        #pragma unroll
        for (int kk = 0; kk < 8; ++kk){
            bf16x8 arf[2], brf[4];
            #pragma unroll
            for (int rt = 0; rt < 2; ++rt)
                arf[rt] = *(const bf16x8*)&h1LDS[(rt * 16 + lm) * 264 + kk * 32 + lq * 8];
            #pragma unroll
            for (int ci = 0; ci < 4; ++ci)
                brf[ci] = *(const bf16x8*)&w2frag[(size_t)((w * 4 + ci) * 8 + kk) * 512 + lane * 8];
            #pragma unroll
            for (int rt = 0; rt < 2; ++rt)
                #pragma unroll
                for (int ci = 0; ci < 4; ++ci)
                    acc[rt][ci] = __builtin_amdgcn_mfma_f32_16x16x32_bf16(brf[ci], arf[rt], acc[rt][ci], 0, 0, 0);
        }

        // lane holds h2[row = rt*16+lm][col = (w*4+ci)*16 + lq*4 + p]
        // ci-outer epilogue keeps weight live-set at one coltile (VGPR bound)
        float m0[2] = {0.f, 0.f}, m1[2] = {0.f, 0.f};
        float l0[2] = {0.f, 0.f}, l1[2] = {0.f, 0.f};
        #pragma unroll
        for (int ci = 0; ci < 4; ++ci){
            int cb = (w * 4 + ci) * 16 + lq * 4;
            f32x4 b2v = *(const f32x4*)&b2[cb];
            f32x4 wmA = *(const f32x4*)&Wmu[cb * 2];
            f32x4 wmB = *(const f32x4*)&Wmu[cb * 2 + 4];
            f32x4 wlA = *(const f32x4*)&Wls[cb * 2];
            f32x4 wlB = *(const f32x4*)&Wls[cb * 2 + 4];
            #pragma unroll
            for (int rt = 0; rt < 2; ++rt){
                float hv0 = fmaxf(acc[rt][ci][0] + b2v[0], 0.f);
                float hv1 = fmaxf(acc[rt][ci][1] + b2v[1], 0.f);
                float hv2 = fmaxf(acc[rt][ci][2] + b2v[2], 0.f);
                float hv3 = fmaxf(acc[rt][ci][3] + b2v[3], 0.f);
                m0[rt] += hv0*wmA[0] + hv1*wmA[2] + hv2*wmB[0] + hv3*wmB[2];
                m1[rt] += hv0*wmA[1] + hv1*wmA[3] + hv2*wmB[1] + hv3*wmB[3];
                l0[rt] += hv0*wlA[0] + hv1*wlA[2] + hv2*wlB[0] + hv3*wlB[2];
                l1[rt] += hv0*wlA[1] + hv1*wlA[3] + hv2*wlB[1] + hv3*wlB[3];
            }
        }
        #pragma unroll
        for (int rt = 0; rt < 2; ++rt){
            float a0 = red4_lq(m0[rt]), a1 = red4_lq(m1[rt]);
            float a2 = red4_lq(l0[rt]), a3 = red4_lq(l1[rt]);
            if (lq == 0){
                f32x4 o = {a0, a1, a2, a3};
                *(f32x4*)&headLDS[(w * 32 + rt * 16 + lm) * 4] = o;
            }
        }
    }
    __syncthreads();

    // ---- phase 4: epilogue, parallel across waves: wave w -> local rows w*8..w*8+7 ----
    if (lane < 8){
        const int rowL = w * 8 + lane;        // 0..31
        f32x4 s = {0.f, 0.f, 0.f, 0.f};
        #pragma unroll
        for (int ww = 0; ww < 4; ++ww)
            s += *(const f32x4*)&headLDS[(ww * 32 + rowL) * 4];
        const size_t grow = (size_t)b * 64 + R0 + rowL;
        float2 nv = *(const float2*)&noise[grow * 2];
        float n0 = nv.x, n1 = nv.y;
        float lp = 0.f;
        {
            float mu = fast_tanh(s[0] + bmu[0]);
            float ls = fast_tanh(s[2] + bls[0]);
            ls = -20.f + 11.f * (ls + 1.f);
            float sd = __builtin_amdgcn_exp2f(ls * 1.4426950408889634f);
            float a = fast_tanh(mu + sd * n0);
            action_out[grow * 2 + 0] = a;
            lp += -0.5f * n0 * n0 - ls - 0.9189385332046727f
                - 0.6931471805599453f * __builtin_amdgcn_logf(1.f - a * a + 1e-7f);
        }
        {
            float mu = fast_tanh(s[1] + bmu[1]);
            float ls = fast_tanh(s[3] + bls[1]);
            ls = -20.f + 11.f * (ls + 1.f);
            float sd = __builtin_amdgcn_exp2f(ls * 1.4426950408889634f);
            float a = fast_tanh(mu + sd * n1);
            action_out[grow * 2 + 1] = a;
            lp += -0.5f * n1 * n1 - ls - 0.9189385332046727f
                - 0.6931471805599453f * __builtin_amdgcn_logf(1.f - a * a + 1e-7f);
        }
        logprob_out[grow] = lp;
    }
}

extern "C" void kernel_launch(void* const* d_in, const int* in_sizes, int n_in,
                              void* d_out, int out_size, void* d_ws, size_t ws_size,
                              hipStream_t stream)
{
    (void)in_sizes; (void)n_in; (void)out_size; (void)ws_size;
    const float* state = (const float*)d_in[0];
    const float* noise = (const float*)d_in[1];
    const float* Wq  = (const float*)d_in[2];
    const float* Wk  = (const float*)d_in[3];
    const float* Wv  = (const float*)d_in[4];
    const float* W1  = (const float*)d_in[5];
    const float* b1  = (const float*)d_in[6];
    const float* W2  = (const float*)d_in[7];
    const float* b2  = (const float*)d_in[8];
    const float* Wmu = (const float*)d_in[9];
    const float* bmu = (const float*)d_in[10];
    const float* Wls = (const float*)d_in[11];
    const float* bls = (const float*)d_in[12];

    unsigned short* w2frag = (unsigned short*)d_ws;   // 65536 bf16
    unsigned short* w1frag = w2frag + 65536;          // 8192 bf16
    float* Cqk = (float*)(w1frag + 8192);             // 120 f32 (16B-aligned)

    float* action_out  = (float*)d_out;
    float* logprob_out = (float*)d_out + (size_t)NROWS * 2;

    prep_kernel<<<130, 256, 0, stream>>>(W2, W1, Wq, Wk, w2frag, w1frag, Cqk);
    actor_kernel<<<2048, 256, 0, stream>>>(state, noise, Cqk, Wv,
        w1frag, b1, w2frag, b2, Wmu, bmu, Wls, bls, action_out, logprob_out);
}

// Round 5
// 110.650 us; speedup vs baseline: 1.0301x; 1.0301x over previous
//
#include <hip/hip_runtime.h>
#include <math.h>

#define NROWS 65536   // B*T = 1024*64

typedef short bf16x8 __attribute__((ext_vector_type(8)));
typedef float f32x4  __attribute__((ext_vector_type(4)));
typedef float f32x2  __attribute__((ext_vector_type(2)));
typedef unsigned int u32x2 __attribute__((ext_vector_type(2)));

__device__ __forceinline__ unsigned short f2bf(float x){
    unsigned int u = __float_as_uint(x);
    u += 0x7FFFu + ((u >> 16) & 1u);      // RNE
    return (unsigned short)(u >> 16);
}
__device__ __forceinline__ unsigned int pkbf(float lo, float hi){
    unsigned int r;
    asm("v_cvt_pk_bf16_f32 %0, %1, %2" : "=v"(r) : "v"(lo), "v"(hi));
    return r;
}
__device__ __forceinline__ f32x2 sp2(float x){ return (f32x2){x, x}; }

template<int CTRL, int RM>
__device__ __forceinline__ float dpp_add(float v){
    int m = __builtin_amdgcn_update_dpp(0, __float_as_int(v), CTRL, RM, 0xF, 1);
    return v + __int_as_float(m);
}
// butterfly over 8 lanes: all 8 lanes get the total
__device__ __forceinline__ float bfly8_add(float v){
    v = dpp_add<0xB1, 0xF>(v);     // quad_perm [1,0,3,2]
    v = dpp_add<0x4E, 0xF>(v);     // quad_perm [2,3,0,1]
    v = dpp_add<0x141, 0xF>(v);    // row_half_mirror
    return v;
}
// sum over the 4 lanes {lm, lm+16, lm+32, lm+48} (reduce over lq)
__device__ __forceinline__ float red4_lq(float v){
    v += __int_as_float(__builtin_amdgcn_ds_swizzle(__float_as_int(v), 0x401F)); // lane^16
    v += __shfl_xor(v, 32, 64);                                                  // lane^32
    return v;
}
__device__ __forceinline__ float fast_tanh(float x){
    float e = __builtin_amdgcn_exp2f(x * 2.8853900817779268f);
    return 1.f - 2.f * __builtin_amdgcn_rcpf(e + 1.f);
}

// ---- prep: weights -> MFMA fragment order; folded qk matrix C ----
__global__ __launch_bounds__(256) void prep_kernel(
    const float* __restrict__ W2, const float* __restrict__ W1,
    const float* __restrict__ Wq, const float* __restrict__ Wk,
    unsigned short* __restrict__ w2frag, unsigned short* __restrict__ w1frag,
    float* __restrict__ Cqk)
{
    const int bx = blockIdx.x, t = threadIdx.x;
    if (bx < 128){
        // coalesced: stage the 32x16 W2 tile through LDS, then frag-order it
        __shared__ float tile[512];           // [kl][cl] = [32][16]
        const int ct = bx >> 3, kk = bx & 7;
        #pragma unroll
        for (int s = 0; s < 2; ++s){
            int flat = t * 2 + s;             // 0..511
            int kl = flat >> 4, cl = flat & 15;
            tile[flat] = W2[(kk * 32 + kl) * 256 + ct * 16 + cl];
        }
        __syncthreads();
        #pragma unroll
        for (int s = 0; s < 2; ++s){
            int f = t * 2 + s;
            int lane = f >> 3, e = f & 7;
            int kl = (lane >> 4) * 8 + e;
            int cl = lane & 15;
            w2frag[(size_t)(ct * 8 + kk) * 512 + f] = f2bf(tile[kl * 16 + cl]);
        }
    } else if (bx == 128){
        #pragma unroll
        for (int s = 0; s < 32; ++s){
            int flat = t * 32 + s;
            int ct = flat >> 9, r = flat & 511;
            int lane = r >> 3, e = r & 7;
            int k = (lane >> 4) * 8 + e;
            int c = ct * 16 + (lane & 15);
            w1frag[flat] = (k < 23) ? f2bf(W1[k * 256 + c]) : (unsigned short)0;
        }
    } else {
        // Cqk[(h*5+f)*8+d] = scale * sum_kk Wk[f*15+h*5+kk] * Wq[d*15+h*5+kk]
        if (t < 120){
            int h = t / 40, rem = t % 40, f = rem >> 3, d = rem & 7;
            float acc = 0.f;
            #pragma unroll
            for (int kk = 0; kk < 5; ++kk)
                acc += Wk[f * 15 + h * 5 + kk] * Wq[d * 15 + h * 5 + kk];
            Cqk[t] = acc * 0.64519834f;   // (1/sqrt5)*log2(e)
        }
    }
}

// ---- fused actor: one block per batch, 512 threads (proven R3 config) ----
__global__ __launch_bounds__(512, 4) void actor_kernel(
    const float* __restrict__ state, const float* __restrict__ noise,
    const float* __restrict__ Cqk,
    const float* __restrict__ Wv,
    const unsigned short* __restrict__ w1frag, const float* __restrict__ b1,
    const unsigned short* __restrict__ w2frag, const float* __restrict__ b2,
    const float* __restrict__ Wmu, const float* __restrict__ bmu,
    const float* __restrict__ Wls, const float* __restrict__ bls,
    float* __restrict__ action_out, float* __restrict__ logprob_out)
{
    // union A: {sLDS 576f, pjLDS 384f, qkLDS 64*20f} then h1LDS (33792 B)
    __shared__ __align__(16) unsigned char uniA[64 * 264 * 2];
    float* sLDS  = (float*)uniA;              // 64*9
    float* pjLDS = sLDS + 576;                // 32*12: pairs (c(j), c(j+32)) for c=s0..3,sn,cs
    float* qkLDS = pjLDS + 384;               // 64*20 prescaled qk (stride 20 -> b128-aligned)
    unsigned short* h1LDS = (unsigned short*)uniA;   // 64 x 264 (stride 264)
    __shared__ __align__(16) unsigned short x0LDS[64 * 40];
    __shared__ __align__(16) float headLDS[8 * 64 * 4];

    const int t    = threadIdx.x;
    const int lane = t & 63;
    const int w    = t >> 6;                  // 0..7
    const int lm   = lane & 15;
    const int lq   = lane >> 4;
    const int b    = blockIdx.x;

    // ---- phase 0 (merged): state load + x0 state-cols + qk fold + sincos ----
    {
        float v = state[(size_t)b * 512 + t];
        int r = t >> 3, c = t & 7;
        sLDS[r * 9 + c] = v;
        if (c < 4) pjLDS[(r & 31) * 12 + c * 2 + (r >> 5)] = v;
        // x0 state columns + zero padding, done here once
        x0LDS[r * 40 + 15 + c] = f2bf(v);
        x0LDS[r * 40 + 23 + c] = 0;
        if (c == 0) x0LDS[r * 40 + 31] = 0;

        if (t < 192){
            const int row = t & 63, h = t >> 6;
            const float* sb = &state[(size_t)b * 512];
            f32x4 sA = *(const f32x4*)&sb[row * 8];
            f32x4 sB = *(const f32x4*)&sb[row * 8 + 4];
            #pragma unroll
            for (int f = 0; f < 5; ++f){
                const float* cp = &Cqk[(h * 5 + f) * 8];
                f32x4 cA = *(const f32x4*)cp;
                f32x4 cB = *(const f32x4*)(cp + 4);
                float acc = sA[0]*cA[0] + sA[1]*cA[1] + sA[2]*cA[2] + sA[3]*cA[3]
                          + sB[0]*cB[0] + sB[1]*cB[1] + sB[2]*cB[2] + sB[3]*cB[3];
                qkLDS[row * 20 + h * 5 + f] = acc;
            }
        } else if (w == 7){
            const int row = lane;
            float ang = 1.5707963267948966f - state[(size_t)b * 512 + row * 8 + 7];
            float sn, cs;
            __sincosf(ang, &sn, &cs);
            int base = (row & 31) * 12 + (row >> 5);
            pjLDS[base + 8]  = sn;
            pjLDS[base + 10] = cs;
        }
    }
    __syncthreads();

    // ---- phase 1: attention, 2 j's per iter via packed fp32; self-term
    //      corrected analytically AFTER the loop (no per-iter masking) ----
    {
        const int il = lane >> 3;
        const int js = lane & 7;
        const int i  = w * 8 + il;
        const float si0 = sLDS[i * 9 + 0], si1 = sLDS[i * 9 + 1];
        const float si2 = sLDS[i * 9 + 2], si3 = sLDS[i * 9 + 3];
        float qkv[16];
        *(f32x4*)&qkv[0]  = *(const f32x4*)&qkLDS[i * 20 + 0];
        *(f32x4*)&qkv[4]  = *(const f32x4*)&qkLDS[i * 20 + 4];
        *(f32x4*)&qkv[8]  = *(const f32x4*)&qkLDS[i * 20 + 8];
        *(f32x4*)&qkv[12] = *(const f32x4*)&qkLDS[i * 20 + 12];

        f32x2 s0 = {0.f,0.f}, s1 = {0.f,0.f}, s2 = {0.f,0.f};
        f32x2 g0[5], g1[5], g2[5];
        #pragma unroll
        for (int f = 0; f < 5; ++f){ g0[f] = sp2(0.f); g1[f] = sp2(0.f); g2[f] = sp2(0.f); }

        #pragma unroll
        for (int jj = 0; jj < 4; ++jj){
            const int jb = jj * 8 + js;                  // handles j = jb and jb+32
            const f32x2* pp = (const f32x2*)&pjLDS[jb * 12];
            f32x2 p0 = pp[0], p1 = pp[1], p2 = pp[2], p3 = pp[3];
            f32x2 sn = pp[4], cs = pp[5];
            f32x2 d0 = p0 - sp2(si0), d1 = p1 - sp2(si1);
            f32x2 d2 = p2 - sp2(si2), d3 = p3 - sp2(si3);
            // r^2 is rotation-invariant; +1e-30 keeps self lane finite
            f32x2 r2v = d0 * d0 + d1 * d1 + sp2(1e-30f);
            f32x2 xn0 = d0 * cs - d1 * sn, yn0 = d0 * sn + d1 * cs;
            f32x2 xn1 = d2 * cs - d3 * sn, yn1 = d2 * sn + d3 * cs;
            f32x2 inv_r;
            inv_r.x = __builtin_amdgcn_rsqf(r2v.x);
            inv_r.y = __builtin_amdgcn_rsqf(r2v.y);
            f32x2 rv  = r2v * inv_r;
            f32x2 arg = rv * sp2(7.2134752f) - sp2(2.8853901f);   // log2(e)*(5r-2)
            f32x2 f4;
            f4.x = __builtin_amdgcn_rcpf(1.f + __builtin_amdgcn_exp2f(arg.x));
            f4.y = __builtin_amdgcn_rcpf(1.f + __builtin_amdgcn_exp2f(arg.y));
            f32x2 f0 = xn0 * inv_r, f1 = yn0 * inv_r;
            f32x2 sc0 = f0*sp2(qkv[0])  + f1*sp2(qkv[1])  + xn1*sp2(qkv[2])  + yn1*sp2(qkv[3])  + f4*sp2(qkv[4]);
            f32x2 sc1 = f0*sp2(qkv[5])  + f1*sp2(qkv[6])  + xn1*sp2(qkv[7])  + yn1*sp2(qkv[8])  + f4*sp2(qkv[9]);
            f32x2 sc2 = f0*sp2(qkv[10]) + f1*sp2(qkv[11]) + xn1*sp2(qkv[12]) + yn1*sp2(qkv[13]) + f4*sp2(qkv[14]);
            f32x2 e0, e1, e2;
            e0.x = __builtin_amdgcn_exp2f(sc0.x);  e0.y = __builtin_amdgcn_exp2f(sc0.y);
            e1.x = __builtin_amdgcn_exp2f(sc1.x);  e1.y = __builtin_amdgcn_exp2f(sc1.y);
            e2.x = __builtin_amdgcn_exp2f(sc2.x);  e2.y = __builtin_amdgcn_exp2f(sc2.y);
            s0 += e0; s1 += e1; s2 += e2;
            g0[0] += e0*f0; g0[1] += e0*f1; g0[2] += e0*xn1; g0[3] += e0*yn1; g0[4] += e0*f4;
            g1[0] += e1*f0; g1[1] += e1*f1; g1[2] += e1*xn1; g1[3] += e1*yn1; g1[4] += e1*f4;
            g2[0] += e2*f0; g2[1] += e2*f1; g2[2] += e2*xn1; g2[3] += e2*yn1; g2[4] += e2*f4;
        }
        // collapse pair lanes, then 8-lane butterfly
        float S0 = s0.x + s0.y, S1 = s1.x + s1.y, S2 = s2.x + s2.y;
        float G0[5], G1[5], G2[5];
        #pragma unroll
        for (int f = 0; f < 5; ++f){
            G0[f] = bfly8_add(g0[f].x + g0[f].y);
            G1[f] = bfly8_add(g1[f].x + g1[f].y);
            G2[f] = bfly8_add(g2[f].x + g2[f].y);
        }
        S0 = bfly8_add(S0); S1 = bfly8_add(S1); S2 = bfly8_add(S2);

        // analytic self-term removal: features at j==i are (0,0,0,0,f4s)
        {
            float argS = 7.2134752e-15f - 2.8853901f;
            float f4s  = __builtin_amdgcn_rcpf(1.f + __builtin_amdgcn_exp2f(argS));
            float es0 = __builtin_amdgcn_exp2f(f4s * qkv[4]);
            float es1 = __builtin_amdgcn_exp2f(f4s * qkv[9]);
            float es2 = __builtin_amdgcn_exp2f(f4s * qkv[14]);
            S0 -= es0; S1 -= es1; S2 -= es2;
            G0[4] -= es0 * f4s; G1[4] -= es1 * f4s; G2[4] -= es2 * f4s;
        }
        float i0 = __builtin_amdgcn_rcpf(S0);
        float i1 = __builtin_amdgcn_rcpf(S1);
        float i2 = __builtin_amdgcn_rcpf(S2);

        // x0: att cols only (state cols + padding written in phase 0)
        #pragma unroll
        for (int mm = 0; mm < 2; ++mm){
            int m = js * 2 + mm;
            if (m < 15){
                float A0 = (m < 5) ? G0[0] : (m < 10) ? G1[0] : G2[0];
                float A1 = (m < 5) ? G0[1] : (m < 10) ? G1[1] : G2[1];
                float A2 = (m < 5) ? G0[2] : (m < 10) ? G1[2] : G2[2];
                float A3 = (m < 5) ? G0[3] : (m < 10) ? G1[3] : G2[3];
                float A4 = (m < 5) ? G0[4] : (m < 10) ? G1[4] : G2[4];
                float I  = (m < 5) ? i0    : (m < 10) ? i1    : i2;
                float av = (A0 * Wv[m] + A1 * Wv[15 + m] + A2 * Wv[30 + m]
                          + A3 * Wv[45 + m] + A4 * Wv[60 + m]) * I;
                x0LDS[i * 40 + m] = f2bf(av);
            }
        }
    }

    // ---- prefetch ALL phase-3 B-fragments (block-invariant, no LDS dep):
    //      issue before the barrier so L2 latency hides under phase 2 ----
    bf16x8 brfp[16];   // [ci*8 + kk]
    #pragma unroll
    for (int q = 0; q < 16; ++q){
        int ci = q >> 3, kk = q & 7;
        brfp[q] = *(const bf16x8*)&w2frag[(size_t)((w * 2 + ci) * 8 + kk) * 512 + lane * 8];
    }
    __builtin_amdgcn_sched_barrier(0);   // keep the loads issued here

    __syncthreads();

    // ---- phase 2: h1^T = mfma(W1^T-frag, x0-frag); cvt_pk + ds_write_b64 ----
    {
        bf16x8 afr[4];
        #pragma unroll
        for (int rt = 0; rt < 4; ++rt)
            afr[rt] = *(const bf16x8*)&x0LDS[(rt * 16 + lm) * 40 + lq * 8];
        #pragma unroll
        for (int ci = 0; ci < 2; ++ci){
            const int ct = w * 2 + ci;
            bf16x8 bfr = *(const bf16x8*)&w1frag[(size_t)ct * 512 + lane * 8];
            f32x4 bb = *(const f32x4*)&b1[ct * 16 + lq * 4];
            #pragma unroll
            for (int rt = 0; rt < 4; ++rt){
                f32x4 c0 = {0.f, 0.f, 0.f, 0.f};
                c0 = __builtin_amdgcn_mfma_f32_16x16x32_bf16(bfr, afr[rt], c0, 0, 0, 0);
                float h0 = fmaxf(c0[0] + bb[0], 0.f);
                float h1v = fmaxf(c0[1] + bb[1], 0.f);
                float h2v = fmaxf(c0[2] + bb[2], 0.f);
                float h3v = fmaxf(c0[3] + bb[3], 0.f);
                u32x2 pk; pk.x = pkbf(h0, h1v); pk.y = pkbf(h2v, h3v);
                *(u32x2*)&h1LDS[(rt * 16 + lm) * 264 + ct * 16 + lq * 4] = pk;
            }
        }
    }
    __syncthreads();

    // ---- phase 3: h2^T = mfma(W2^T-frag, h1-frag), B-frags already in regs ----
    {
        f32x4 acc[4][2];
        #pragma unroll
        for (int rt = 0; rt < 4; ++rt)
            #pragma unroll
            for (int ci = 0; ci < 2; ++ci) acc[rt][ci] = (f32x4){0.f, 0.f, 0.f, 0.f};

        #pragma unroll
        for (int kk = 0; kk < 8; ++kk){
            bf16x8 arf[4];
            #pragma unroll
            for (int rt = 0; rt < 4; ++rt)
                arf[rt] = *(const bf16x8*)&h1LDS[(rt * 16 + lm) * 264 + kk * 32 + lq * 8];
            #pragma unroll
            for (int rt = 0; rt < 4; ++rt)
                #pragma unroll
                for (int ci = 0; ci < 2; ++ci)
                    acc[rt][ci] = __builtin_amdgcn_mfma_f32_16x16x32_bf16(brfp[ci * 8 + kk], arf[rt], acc[rt][ci], 0, 0, 0);
        }

        // lane holds h2[row = rt*16+lm][col = (w*2+ci)*16 + lq*4 + p]
        f32x4 b2v[2], wmA[2], wmB[2], wlA[2], wlB[2];
        #pragma unroll
        for (int ci = 0; ci < 2; ++ci){
            int cb = (w * 2 + ci) * 16 + lq * 4;
            b2v[ci] = *(const f32x4*)&b2[cb];
            wmA[ci] = *(const f32x4*)&Wmu[cb * 2];
            wmB[ci] = *(const f32x4*)&Wmu[cb * 2 + 4];
            wlA[ci] = *(const f32x4*)&Wls[cb * 2];
            wlB[ci] = *(const f32x4*)&Wls[cb * 2 + 4];
        }
        #pragma unroll
        for (int rt = 0; rt < 4; ++rt){
            float m0 = 0.f, m1 = 0.f, l0 = 0.f, l1 = 0.f;
            #pragma unroll
            for (int ci = 0; ci < 2; ++ci){
                float hv0 = fmaxf(acc[rt][ci][0] + b2v[ci][0], 0.f);
                float hv1 = fmaxf(acc[rt][ci][1] + b2v[ci][1], 0.f);
                float hv2 = fmaxf(acc[rt][ci][2] + b2v[ci][2], 0.f);
                float hv3 = fmaxf(acc[rt][ci][3] + b2v[ci][3], 0.f);
                m0 += hv0*wmA[ci][0] + hv1*wmA[ci][2] + hv2*wmB[ci][0] + hv3*wmB[ci][2];
                m1 += hv0*wmA[ci][1] + hv1*wmA[ci][3] + hv2*wmB[ci][1] + hv3*wmB[ci][3];
                l0 += hv0*wlA[ci][0] + hv1*wlA[ci][2] + hv2*wlB[ci][0] + hv3*wlB[ci][2];
                l1 += hv0*wlA[ci][1] + hv1*wlA[ci][3] + hv2*wlB[ci][1] + hv3*wlB[ci][3];
            }
            m0 = red4_lq(m0); m1 = red4_lq(m1);
            l0 = red4_lq(l0); l1 = red4_lq(l1);
            if (lq == 0){
                f32x4 o = {m0, m1, l0, l1};
                *(f32x4*)&headLDS[(w * 64 + rt * 16 + lm) * 4] = o;
            }
        }
    }
    __syncthreads();

    // ---- phase 4: epilogue, parallel across waves: wave w -> rows w*8..w*8+7 ----
    if (lane < 8){
        const int row = w * 8 + lane;
        f32x4 s = {0.f, 0.f, 0.f, 0.f};
        #pragma unroll
        for (int ww = 0; ww < 8; ++ww)
            s += *(const f32x4*)&headLDS[(ww * 64 + row) * 4];
        const size_t grow = (size_t)b * 64 + row;
        float2 nv = *(const float2*)&noise[grow * 2];
        float n0 = nv.x, n1 = nv.y;
        float lp = 0.f;
        {
            float mu = fast_tanh(s[0] + bmu[0]);
            float ls = fast_tanh(s[2] + bls[0]);
            ls = -20.f + 11.f * (ls + 1.f);
            float sd = __builtin_amdgcn_exp2f(ls * 1.4426950408889634f);
            float a = fast_tanh(mu + sd * n0);
            action_out[grow * 2 + 0] = a;
            lp += -0.5f * n0 * n0 - ls - 0.9189385332046727f
                - 0.6931471805599453f * __builtin_amdgcn_logf(1.f - a * a + 1e-7f);
        }
        {
            float mu = fast_tanh(s[1] + bmu[1]);
            float ls = fast_tanh(s[3] + bls[1]);
            ls = -20.f + 11.f * (ls + 1.f);
            float sd = __builtin_amdgcn_exp2f(ls * 1.4426950408889634f);
            float a = fast_tanh(mu + sd * n1);
            action_out[grow * 2 + 1] = a;
            lp += -0.5f * n1 * n1 - ls - 0.9189385332046727f
                - 0.6931471805599453f * __builtin_amdgcn_logf(1.f - a * a + 1e-7f);
        }
        logprob_out[grow] = lp;
    }
}

extern "C" void kernel_launch(void* const* d_in, const int* in_sizes, int n_in,
                              void* d_out, int out_size, void* d_ws, size_t ws_size,
                              hipStream_t stream)
{
    (void)in_sizes; (void)n_in; (void)out_size; (void)ws_size;
    const float* state = (const float*)d_in[0];
    const float* noise = (const float*)d_in[1];
    const float* Wq  = (const float*)d_in[2];
    const float* Wk  = (const float*)d_in[3];
    const float* Wv  = (const float*)d_in[4];
    const float* W1  = (const float*)d_in[5];
    const float* b1  = (const float*)d_in[6];
    const float* W2  = (const float*)d_in[7];
    const float* b2  = (const float*)d_in[8];
    const float* Wmu = (const float*)d_in[9];
    const float* bmu = (const float*)d_in[10];
    const float* Wls = (const float*)d_in[11];
    const float* bls = (const float*)d_in[12];

    unsigned short* w2frag = (unsigned short*)d_ws;   // 65536 bf16
    unsigned short* w1frag = w2frag + 65536;          // 8192 bf16
    float* Cqk = (float*)(w1frag + 8192);             // 120 f32 (16B-aligned)

    float* action_out  = (float*)d_out;
    float* logprob_out = (float*)d_out + (size_t)NROWS * 2;

    prep_kernel<<<130, 256, 0, stream>>>(W2, W1, Wq, Wk, w2frag, w1frag, Cqk);
    actor_kernel<<<1024, 512, 0, stream>>>(state, noise, Cqk, Wv,
        w1frag, b1, w2frag, b2, Wmu, bmu, Wls, bls, action_out, logprob_out);
}